// Round 5
// baseline (1196.339 us; speedup 1.0000x reference)
//
#include <hip/hip_runtime.h>
#include <cstdint>
#include <cstddef>

// Match numpy/XLA float32 semantics: no FMA contraction anywhere.
#pragma clang fp contract(off)

#define KCLS 9
#define PRE_N 6000
#define POST_N 300
#define NMS_IOU_T 0.7f
#define CHUNKS 32
#define HBLOCK 256
#define PICK_BLOCK 256
#define NMS_BLOCK 1024
#define TIE_CAP 2048

// ---------------- shared decode (reference float32 op order) ----------------
__device__ __forceinline__ void decode_box(const float* __restrict__ deltas,
                                           const float* __restrict__ anchors,
                                           int img, int A, unsigned idx,
                                           float* __restrict__ ob /*4 floats*/) {
    float a0 = anchors[(size_t)idx * 4 + 0];
    float a1 = anchors[(size_t)idx * 4 + 1];
    float a2 = anchors[(size_t)idx * 4 + 2];
    float a3 = anchors[(size_t)idx * 4 + 3];
    const float* dd = deltas + ((size_t)img * A + idx) * 4;
    float d0 = dd[0] * 0.1f;
    float d1 = dd[1] * 0.1f;
    float d2 = dd[2] * 0.2f;
    float d3 = dd[3] * 0.2f;
    float anc_w = a3 - a1;
    float anc_h = a2 - a0;
    float anc_cx = a1 + 0.5f * anc_w;
    float anc_cy = a0 + 0.5f * anc_h;
    float bb_w = expf(d3) * anc_w;
    float bb_h = expf(d2) * anc_h;
    float bb_cx = d1 * anc_w + anc_cx;
    float bb_cy = d0 * anc_h + anc_cy;
    float y1 = bb_cy - 0.5f * bb_h;
    float x1 = bb_cx - 0.5f * bb_w;
    float y2 = bb_h + y1;
    float x2 = bb_w + x1;
    ob[0] = y1; ob[1] = x1; ob[2] = y2; ob[3] = x2;
}

// ---------------- stage 1: fused softmax + radix histogram pass 1 ----------------
// grid (CHUNKS, B), 256 thr. 512 groups/block, 2 groups/thread.
__global__ void __launch_bounds__(HBLOCK)
softmax_hist_kernel(const float* __restrict__ labels,
                    float* __restrict__ scores,
                    unsigned int* __restrict__ ghist,  // [B][2048], pass-1 bins = bits >> 21
                    int A) {
    __shared__ unsigned int h[2048];
    const int img = blockIdx.y;
    const int chunk = blockIdx.x;
    const int tid = threadIdx.x;
    const int groups = A / KCLS;
    const int gpc = groups / CHUNKS;    // 512
    for (int i = tid; i < 2048; i += HBLOCK) h[i] = 0u;
    __syncthreads();
    for (int gl = tid; gl < gpc; gl += HBLOCK) {
        int g = chunk * gpc + gl;
        const float* x = labels + (size_t)img * A + (size_t)g * KCLS;
        float v[KCLS];
        float m = -1e30f;
        #pragma unroll
        for (int k = 0; k < KCLS; ++k) { v[k] = x[k]; m = fmaxf(m, v[k]); }
        float e[KCLS];
        float s = 0.f;
        #pragma unroll
        for (int k = 0; k < KCLS; ++k) { e[k] = expf(v[k] - m); s += e[k]; }
        float* o = scores + (size_t)img * A + (size_t)g * KCLS;
        #pragma unroll
        for (int k = 0; k < KCLS; ++k) {
            float p = e[k] / s;
            o[k] = p;
            atomicAdd(&h[__float_as_uint(p) >> 21], 1u);
        }
    }
    __syncthreads();
    unsigned int* gh = ghist + (size_t)img * 2048;
    for (int i = tid; i < 2048; i += HBLOCK) {
        unsigned int c = h[i];
        if (c) atomicAdd(&gh[i], c);
    }
}

// ---------------- radix histogram passes 2/3 (spread over 1024 blocks) ----------------
__global__ void __launch_bounds__(HBLOCK)
hist_kernel(const float* __restrict__ scores,
            unsigned int* __restrict__ ghist,        // [B][2048]
            const unsigned int* __restrict__ state,  // [B][2] {prefix,krem}
            int A, int shift, int bins, unsigned int pmask) {
    __shared__ unsigned int h[2048];
    const int img = blockIdx.y;
    const int chunk = blockIdx.x;
    const int tid = threadIdx.x;
    for (int i = tid; i < bins; i += HBLOCK) h[i] = 0u;
    __syncthreads();
    unsigned int prefix = state[img * 2 + 0] & pmask;
    const int per = A / CHUNKS;
    const float* sc = scores + (size_t)img * A + (size_t)chunk * per;
    for (int i = tid; i < per; i += HBLOCK) {
        unsigned int v = __float_as_uint(sc[i]);   // scores > 0: uint order == float order
        if ((v & pmask) == prefix)
            atomicAdd(&h[(v >> shift) & (unsigned)(bins - 1)], 1u);
    }
    __syncthreads();
    unsigned int* gh = ghist + (size_t)img * 2048;
    for (int i = tid; i < bins; i += HBLOCK) {
        unsigned int c = h[i];
        if (c) atomicAdd(&gh[i], c);
    }
}

// ---------------- pick target bin (parallel suffix scan) ----------------
__global__ void __launch_bounds__(PICK_BLOCK)
pick_kernel(const unsigned int* __restrict__ ghist,
            unsigned int* __restrict__ state,
            int shift, int bins, int first_pass) {
    const int img = blockIdx.x;
    const int t = threadIdx.x;
    const unsigned int* gh = ghist + (size_t)img * 2048;
    __shared__ unsigned int cnt[2048];
    __shared__ unsigned int ssum[PICK_BLOCK];
    const int per = bins / PICK_BLOCK;   // 8 or 4
    unsigned int my = 0;
    for (int i = 0; i < per; ++i) {
        unsigned int c = gh[t * per + i];
        cnt[t * per + i] = c;
        my += c;
    }
    ssum[t] = my;
    __syncthreads();
    // inclusive suffix scan: ssum[t] = sum_{u >= t} chunk_sum[u]
    for (int d = 1; d < PICK_BLOCK; d <<= 1) {
        unsigned int v = (t + d < PICK_BLOCK) ? ssum[t + d] : 0u;
        __syncthreads();
        ssum[t] += v;
        __syncthreads();
    }
    unsigned int prefix = first_pass ? 0u : state[img * 2 + 0];
    unsigned int krem = first_pass ? (unsigned)PRE_N : state[img * 2 + 1];
    unsigned int above = ssum[t] - my;   // strictly above my chunk
    if (above < krem && ssum[t] >= krem) {   // unique thread
        unsigned int cum = above;
        for (int b = per - 1; b >= 0; --b) {
            unsigned int c = cnt[t * per + b];
            if (cum + c >= krem) {
                state[img * 2 + 0] = prefix | ((unsigned int)(t * per + b) << shift);
                state[img * 2 + 1] = krem - cum;
                break;
            }
            cum += c;
        }
    }
}

// ---------------- push + decode (spread): scores > T scatter to pre arrays ----------------
// key = (score_bits << 32) | ~index  -> u64 max order == (score desc, index asc),
// identical to lax.top_k + argmax tie semantics. No sort needed.
__global__ void __launch_bounds__(HBLOCK)
push_decode_kernel(const float* __restrict__ scores,
                   const float* __restrict__ deltas,
                   const float* __restrict__ anchors,
                   const unsigned int* __restrict__ state,
                   unsigned int* __restrict__ cntg,    // [B], zeroed
                   unsigned int* __restrict__ tiecnt,  // [B], zeroed
                   unsigned int* __restrict__ tieIdx,  // [B][TIE_CAP]
                   float* __restrict__ pre_boxes,      // [B][6000][4]
                   unsigned long long* __restrict__ pre_key,  // [B][6000]
                   int A) {
    const int img = blockIdx.y;
    const int chunk = blockIdx.x;
    const int tid = threadIdx.x;
    const int lane = tid & 63;
    const unsigned int T = state[img * 2 + 0];
    const int per = A / CHUNKS;
    const int base_i = chunk * per;
    const float* sc = scores + (size_t)img * A;
    for (int i = tid; i < per; i += HBLOCK) {
        int gi = base_i + i;
        unsigned int v = __float_as_uint(sc[gi]);
        bool push = (v > T);
        unsigned long long bal = __ballot(push ? 1 : 0);
        if (push) {
            int leader = __ffsll(bal) - 1;
            int rank = __popcll(bal & ((1ull << lane) - 1ull));
            unsigned int base = 0;
            if (lane == leader)
                base = atomicAdd(&cntg[img], (unsigned int)__popcll(bal));
            base = (unsigned int)__shfl((int)base, leader);
            unsigned int pos = base + (unsigned int)rank;   // < 6000 guaranteed
            float ob[4];
            decode_box(deltas, anchors, img, A, (unsigned)gi, ob);
            float* pb = pre_boxes + ((size_t)img * PRE_N + pos) * 4;
            pb[0] = ob[0]; pb[1] = ob[1]; pb[2] = ob[2]; pb[3] = ob[3];
            pre_key[(size_t)img * PRE_N + pos] =
                ((unsigned long long)v << 32) | (unsigned long long)(~(unsigned)gi);
        }
        if (v == T) {
            unsigned int t = atomicAdd(&tiecnt[img], 1u);
            if (t < TIE_CAP) tieIdx[(size_t)img * TIE_CAP + t] = (unsigned)gi;
        }
    }
}

// ---------------- tie resolve: take the krem smallest-index elements == T ----------------
__global__ void __launch_bounds__(256)
tie_kernel(const float* __restrict__ deltas,
           const float* __restrict__ anchors,
           const unsigned int* __restrict__ state,
           const unsigned int* __restrict__ tiecnt,
           const unsigned int* __restrict__ tieIdx,
           float* __restrict__ pre_boxes,
           unsigned long long* __restrict__ pre_key,
           int A) {
    const int img = blockIdx.x;
    const int tid = threadIdx.x;
    const unsigned int T = state[img * 2 + 0];
    const unsigned int krem = state[img * 2 + 1];
    int n = (int)tiecnt[img];
    if (n > TIE_CAP) n = TIE_CAP;
    const unsigned int* ti = tieIdx + (size_t)img * TIE_CAP;
    const unsigned int base = (unsigned)PRE_N - krem;
    for (int e = tid; e < n; e += 256) {
        unsigned int idx_e = ti[e];
        unsigned int rank = 0;
        for (int j = 0; j < n; ++j) rank += (ti[j] < idx_e) ? 1u : 0u;
        if (rank < krem) {
            unsigned int pos = base + rank;
            float ob[4];
            decode_box(deltas, anchors, img, A, idx_e, ob);
            float* pb = pre_boxes + ((size_t)img * PRE_N + pos) * 4;
            pb[0] = ob[0]; pb[1] = ob[1]; pb[2] = ob[2]; pb[3] = ob[3];
            pre_key[(size_t)img * PRE_N + pos] =
                ((unsigned long long)T << 32) | (unsigned long long)(~idx_e);
        }
    }
}

// ---------------- stage 3: greedy NMS over UNSORTED set via u64 max-key ----------------
// Explicit named scalars (no arrays) so nothing can be demoted to scratch
// (rounds 2/3: VGPR=48/80 + FETCH 1.6/1.9 GB = per-iteration scratch reload).
// key==0 means dead; pivot self-suppresses via IoU≈1.
#define PER 6    // 1024 threads * 6 slots = 6144 >= 6000

#define LOADC(s) \
    float y1_##s = 0.f, x1_##s = 0.f, y2_##s = 0.f, x2_##s = 0.f, ar_##s = 0.f; \
    unsigned long long k_##s = 0ull; \
    { int j = tid + (s) * NMS_BLOCK; \
      if (j < PRE_N) { \
        float4 b4 = bb4[j]; \
        y1_##s = b4.x; x1_##s = b4.y; y2_##s = b4.z; x2_##s = b4.w; \
        ar_##s = (b4.z - b4.x) * (b4.w - b4.y); \
        k_##s = keys[j]; } }

#define MAXC(s) if (k_##s > m) m = k_##s;

#define PUBC(s) \
    else if (k_##s == w) { \
        sPiv[0] = y1_##s; sPiv[1] = x1_##s; sPiv[2] = y2_##s; sPiv[3] = x2_##s; sPiv[4] = ar_##s; \
        float* ob = ob_base + it * 4; \
        ob[0] = y1_##s; ob[1] = x1_##s; ob[2] = y2_##s; ob[3] = x2_##s; \
        os_base[it] = __uint_as_float((unsigned int)(w >> 32)); }

#define UPDC(s) { \
    float iy1 = fmaxf(py1, y1_##s); \
    float ix1 = fmaxf(px1, x1_##s); \
    float iy2 = fminf(py2, y2_##s); \
    float ix2 = fminf(px2, x2_##s); \
    float ih = iy2 - iy1; ih = ih > 0.f ? ih : 0.f; \
    float iw = ix2 - ix1; iw = iw > 0.f ? iw : 0.f; \
    float inter = ih * iw; \
    float den = ar_##s + pa - inter + 1e-9f; \
    float hi = 0.7000007f * den; \
    bool sup = inter > hi; \
    float lo = 0.6999993f * den; \
    if (inter >= lo && inter <= hi) sup = (inter / den) > NMS_IOU_T; \
    if (sup) k_##s = 0ull; }

__global__ void __launch_bounds__(NMS_BLOCK, 4)
nms_kernel(const float* __restrict__ pre_boxes,
           const unsigned long long* __restrict__ pre_key,
           float* __restrict__ out_boxes,    // [B][300][4]
           float* __restrict__ out_scores) { // [B][300]
    const int img = blockIdx.x;
    const int tid = threadIdx.x;
    const int lane = tid & 63;
    const float4* bb4 = (const float4*)(pre_boxes + (size_t)img * PRE_N * 4);
    const unsigned long long* keys = pre_key + (size_t)img * PRE_N;
    float* ob_base = out_boxes + (size_t)img * POST_N * 4;
    float* os_base = out_scores + (size_t)img * POST_N;

    // pre-zero this image's output rows (rows past last pick must be 0)
    for (int i = tid; i < POST_N * 4; i += NMS_BLOCK) ob_base[i] = 0.f;
    for (int i = tid; i < POST_N; i += NMS_BLOCK) os_base[i] = 0.f;

    LOADC(0) LOADC(1) LOADC(2) LOADC(3) LOADC(4) LOADC(5)

    __shared__ unsigned long long slot[2];
    __shared__ float sPiv[5];
    if (tid == 0) { slot[0] = 0ull; slot[1] = 0ull; }
    __syncthreads();

    for (int it = 0; it < POST_N; ++it) {
        const int c = it & 1;
        unsigned long long m = k_0;
        MAXC(1) MAXC(2) MAXC(3) MAXC(4) MAXC(5)
        #pragma unroll
        for (int off = 32; off > 0; off >>= 1) {
            unsigned long long o = __shfl_down(m, off);
            if (o > m) m = o;
        }
        if (lane == 0 && m) atomicMax(&slot[c], m);
        if (tid == 0) slot[c ^ 1] = 0ull;      // idle slot this window: race-free
        __syncthreads();                        // (A) all maxes posted
        unsigned long long w = slot[c];
        if (w == 0ull) break;                   // uniform: all suppressed; rest stays zero

        if (false) {} PUBC(0) PUBC(1) PUBC(2) PUBC(3) PUBC(4) PUBC(5)
        __syncthreads();                        // (B) pivot visible
        float py1 = sPiv[0], px1 = sPiv[1], py2 = sPiv[2], px2 = sPiv[3], pa = sPiv[4];
        UPDC(0) UPDC(1) UPDC(2) UPDC(3) UPDC(4) UPDC(5)
    }
}

extern "C" void kernel_launch(void* const* d_in, const int* in_sizes, int n_in,
                              void* d_out, int out_size, void* d_ws, size_t ws_size,
                              hipStream_t stream) {
    const float* deltas  = (const float*)d_in[0];  // (B, A, 4)
    const float* labels  = (const float*)d_in[1];  // (B, FH, FW, 9)
    const float* anchors = (const float*)d_in[2];  // (A, 4)
    float* out = (float*)d_out;

    const int A = in_sizes[2] / 4;                 // 147456
    const int B = in_sizes[0] / (A * 4);           // 32

    // workspace layout
    float* scores = (float*)d_ws;                                          // B*A
    float* pre_boxes = scores + (size_t)B * A;                             // B*6000*4
    unsigned long long* pre_key = (unsigned long long*)(pre_boxes + (size_t)B * PRE_N * 4);  // B*6000 (8B-aligned)
    unsigned int* hist   = (unsigned int*)(pre_key + (size_t)B * PRE_N);   // 3*B*2048
    unsigned int* cntg   = hist + (size_t)3 * B * 2048;                    // B
    unsigned int* tiecnt = cntg + B;                                       // B
    unsigned int* state  = tiecnt + B;                                     // B*2
    unsigned int* tieIdx = state + (size_t)2 * B;                          // B*TIE_CAP

    float* out_boxes  = out;                        // B*300*4
    float* out_scores = out + (size_t)B * POST_N * 4;

    // zero hist + cntg + tiecnt in one contiguous memset
    hipMemsetAsync(hist, 0, ((size_t)3 * B * 2048 + 2 * (size_t)B) * sizeof(unsigned int), stream);

    dim3 hgrid(CHUNKS, B);
    // pass 1 fused with softmax: bits [31:21]
    softmax_hist_kernel<<<hgrid, HBLOCK, 0, stream>>>(labels, scores, hist + (size_t)0 * B * 2048, A);
    pick_kernel<<<B, PICK_BLOCK, 0, stream>>>(hist + (size_t)0 * B * 2048, state, 21, 2048, 1);
    // pass 2: bits [20:10]
    hist_kernel<<<hgrid, HBLOCK, 0, stream>>>(scores, hist + (size_t)1 * B * 2048, state, A, 10, 2048, 0xFFE00000u);
    pick_kernel<<<B, PICK_BLOCK, 0, stream>>>(hist + (size_t)1 * B * 2048, state, 10, 2048, 0);
    // pass 3: bits [9:0]
    hist_kernel<<<hgrid, HBLOCK, 0, stream>>>(scores, hist + (size_t)2 * B * 2048, state, A, 0, 1024, 0xFFFFFC00u);
    pick_kernel<<<B, PICK_BLOCK, 0, stream>>>(hist + (size_t)2 * B * 2048, state, 0, 1024, 0);

    push_decode_kernel<<<hgrid, HBLOCK, 0, stream>>>(scores, deltas, anchors, state,
                                                     cntg, tiecnt, tieIdx, pre_boxes, pre_key, A);
    tie_kernel<<<B, 256, 0, stream>>>(deltas, anchors, state, tiecnt, tieIdx, pre_boxes, pre_key, A);

    nms_kernel<<<B, NMS_BLOCK, 0, stream>>>(pre_boxes, pre_key, out_boxes, out_scores);
}